// Round 16
// baseline (50.896 us; speedup 1.0000x reference)
//
#include <hip/hip_runtime.h>

// CharacteristicLineEncoder: B=4096, DIM=3, L=300, S=60, P=5, E=128
//   K1: gf[b,e] = relu(sum_l W_gn[l]*relu(W_ge[e,:]·x[b,:,l]+b_ge[e]) + b_gn)
//       (R13's proven kernel, unchanged)
//   K2: one WAVE per (b, tile of 12 regions): grid (5, 4096), 64 threads,
//       no LDS, no barriers, x via uniform scalar loads (720B window),
//       12 named v2f accumulators, 12 streaming dwordx2 stores.
// Rationale (R15 post-mortem): 8 structurally different kernels all land at
// 45.6-52us; every per-pipe theory falsified. Invariant = coarse per-block
// serial shape with tail-burst stores. K2 shrinks work unit 5x and removes
// intra-block sync so resident blocks sit at different life phases ->
// store traffic spreads over the whole kernel.

typedef float v2f __attribute__((ext_vector_type(2)));

#define PKFMA(a, b, c) __builtin_elementwise_fma((a), (b), (c))
#define PKRELU(a)      __builtin_elementwise_max((a), (v2f)0.0f)
#define SPLAT(s)       ((v2f)(s))

// ---------------- Kernel 1: global branch -> gf (proven in R13) ----------------
__global__ __launch_bounds__(256) void cle_global(
    const float* __restrict__ x,     // [B,3,300]
    const float* __restrict__ W_ge,  // [E,3]
    const float* __restrict__ b_ge,  // [E]
    const float* __restrict__ W_gn,  // [300]
    const float* __restrict__ b_gn,  // [1]
    float* __restrict__ gf_out)      // [B,128] in d_ws
{
    const int tid  = threadIdx.x;
    const int lane = tid & 63;
    const int wq   = __builtin_amdgcn_readfirstlane(tid >> 6);  // 0..3
    const int b    = blockIdx.x;
    const int e0   = lane << 1;

    __shared__ __align__(16) float4 sx4[225];
    __shared__ v2f sgp[4][64];

    if (tid < 225) sx4[tid] = ((const float4*)(x + (size_t)b * 900))[tid];

    const v2f wg0 = {W_ge[e0 * 3 + 0], W_ge[e0 * 3 + 3]};
    const v2f wg1 = {W_ge[e0 * 3 + 1], W_ge[e0 * 3 + 4]};
    const v2f wg2 = {W_ge[e0 * 3 + 2], W_ge[e0 * 3 + 5]};
    const v2f bg  = {b_ge[e0], b_ge[e0 + 1]};
    const float bgn = b_gn[0];

    __syncthreads();

#define GE(cmp) PKRELU(PKFMA(wg2, SPLAT(c2.cmp), PKFMA(wg1, SPLAT(c1.cmp), PKFMA(wg0, SPLAT(c0.cmp), bg))))

    v2f ga0 = SPLAT(0.f), ga1 = SPLAT(0.f), ga2 = SPLAT(0.f), ga3 = SPLAT(0.f);
    {
        const int qb = wq * 20;
        const int nq = (wq < 3) ? 20 : 15;   // SGPR
        for (int g = 0; g < 4; ++g) {
            if (g * 5 < nq) {                // wave-uniform guard
#pragma unroll
                for (int qi = 0; qi < 5; ++qi) {
                    const int qq = qb + g * 5 + qi;
                    const int l4 = qq * 4;   // uniform -> W_gn scalarizes
                    const float4 c0 = sx4[qq], c1 = sx4[75 + qq], c2 = sx4[150 + qq];
                    ga0 = PKFMA(SPLAT(W_gn[l4 + 0]), GE(x), ga0);
                    ga1 = PKFMA(SPLAT(W_gn[l4 + 1]), GE(y), ga1);
                    ga2 = PKFMA(SPLAT(W_gn[l4 + 2]), GE(z), ga2);
                    ga3 = PKFMA(SPLAT(W_gn[l4 + 3]), GE(w), ga3);
                }
            }
        }
    }
    sgp[wq][lane] = (ga0 + ga1) + (ga2 + ga3);
    __syncthreads();

    if (wq == 0) {
        const v2f p0 = sgp[0][lane], p1 = sgp[1][lane];
        const v2f p2 = sgp[2][lane], p3 = sgp[3][lane];
        const v2f gf = PKRELU(((p0 + p1) + (p2 + p3)) + SPLAT(bgn));
        ((v2f*)gf_out)[(size_t)b * 64 + lane] = gf;
    }
}

// ------- Kernel 2: one wave per (b, 12-region tile); no LDS, no barriers -------
__global__ __launch_bounds__(64) void cle_local(
    const float* __restrict__ x,     // [B,3,300]
    const float* __restrict__ W_le,  // [E,3]
    const float* __restrict__ b_le,  // [E]
    const float* __restrict__ W_lr,  // [300]
    const float* __restrict__ b_lr,  // [60]
    const float* __restrict__ gf_in, // [B,128] in d_ws
    float* __restrict__ out)         // [B,60,128]
{
    const int lane = threadIdx.x;    // 0..63
    const int t    = blockIdx.x;     // tile 0..4 (uniform)
    const int b    = blockIdx.y;     // batch element (uniform)
    const int e0   = lane << 1;

    const float* __restrict__ xb = x + (size_t)b * 900;   // uniform base

    // per-lane packed (e0,e1) weights + gf
    const v2f wl0 = {W_le[e0 * 3 + 0], W_le[e0 * 3 + 3]};
    const v2f wl1 = {W_le[e0 * 3 + 1], W_le[e0 * 3 + 4]};
    const v2f wl2 = {W_le[e0 * 3 + 2], W_le[e0 * 3 + 5]};
    const v2f bl  = {b_le[e0], b_le[e0 + 1]};
    const v2f gf  = ((const v2f*)gf_in)[(size_t)b * 64 + lane];

    // 12 local accumulators, NAMED, literal indices only (rule #20)
    v2f A00 = SPLAT(0.f), A01 = SPLAT(0.f), A02 = SPLAT(0.f), A03 = SPLAT(0.f);
    v2f A10 = SPLAT(0.f), A11 = SPLAT(0.f), A12 = SPLAT(0.f), A13 = SPLAT(0.f);
    v2f A20 = SPLAT(0.f), A21 = SPLAT(0.f), A22 = SPLAT(0.f), A23 = SPLAT(0.f);

#define LEj(j) PKRELU(PKFMA(wl2, SPLAT(c2##j), PKFMA(wl1, SPLAT(c1##j), PKFMA(wl0, SPLAT(c0##j), bl))))

    // one quad = 4 l: 12 uniform scalar x-loads (s_load path), local branch only
#define DOQ(qi, A0, A1, A2, A3)                                                \
    {                                                                          \
        const int lq = lbase + (qi) * 4;     /* uniform */                     \
        const float c00 = xb[lq + 0],   c01 = xb[lq + 1];                      \
        const float c02 = xb[lq + 2],   c03 = xb[lq + 3];                      \
        const float c10 = xb[300 + lq + 0], c11 = xb[300 + lq + 1];            \
        const float c12 = xb[300 + lq + 2], c13 = xb[300 + lq + 3];            \
        const float c20 = xb[600 + lq + 0], c21 = xb[600 + lq + 1];            \
        const float c22 = xb[600 + lq + 2], c23 = xb[600 + lq + 3];            \
        A0 = PKFMA(SPLAT(W_lr[lq + 0]), LEj(0), A0);                           \
        A1 = PKFMA(SPLAT(W_lr[lq + 1]), LEj(1), A1);                           \
        A2 = PKFMA(SPLAT(W_lr[lq + 2]), LEj(2), A2);                           \
        A3 = PKFMA(SPLAT(W_lr[lq + 3]), LEj(3), A3);                           \
    }

    // tile t owns l = 60t..60t+59 = regions 12t..12t+11, 3 groups of 4 regions
    // element tt = 4*qi + j (l = 60t + 20g + tt), region = 12t + 4g + tt/5
    {
        const int lbase = t * 60;            // group 0: regions 12t+0..3
        DOQ(0, A00, A00, A00, A00)           // tt 0..3
        DOQ(1, A00, A01, A01, A01)           // tt 4..7
        DOQ(2, A01, A01, A02, A02)           // tt 8..11
        DOQ(3, A02, A02, A02, A03)           // tt 12..15
        DOQ(4, A03, A03, A03, A03)           // tt 16..19
    }
    {
        const int lbase = t * 60 + 20;       // group 1: regions 12t+4..7
        DOQ(0, A10, A10, A10, A10)
        DOQ(1, A10, A11, A11, A11)
        DOQ(2, A11, A11, A12, A12)
        DOQ(3, A12, A12, A12, A13)
        DOQ(4, A13, A13, A13, A13)
    }
    {
        const int lbase = t * 60 + 40;       // group 2: regions 12t+8..11
        DOQ(0, A20, A20, A20, A20)
        DOQ(1, A20, A21, A21, A21)
        DOQ(2, A21, A21, A22, A22)
        DOQ(3, A22, A22, A22, A23)
        DOQ(4, A23, A23, A23, A23)
    }

    // stores: regions s0 = 12t .. 12t+11 (each 512B contiguous per wave)
    v2f* ob2 = (v2f*)(out + (size_t)b * (60 * 128)) + lane;   // + s*64
    const int s0 = t * 12;                   // uniform -> b_lr scalar
    ob2[(s0 +  0) * 64] = A00 + gf + SPLAT(b_lr[s0 +  0]);
    ob2[(s0 +  1) * 64] = A01 + gf + SPLAT(b_lr[s0 +  1]);
    ob2[(s0 +  2) * 64] = A02 + gf + SPLAT(b_lr[s0 +  2]);
    ob2[(s0 +  3) * 64] = A03 + gf + SPLAT(b_lr[s0 +  3]);
    ob2[(s0 +  4) * 64] = A10 + gf + SPLAT(b_lr[s0 +  4]);
    ob2[(s0 +  5) * 64] = A11 + gf + SPLAT(b_lr[s0 +  5]);
    ob2[(s0 +  6) * 64] = A12 + gf + SPLAT(b_lr[s0 +  6]);
    ob2[(s0 +  7) * 64] = A13 + gf + SPLAT(b_lr[s0 +  7]);
    ob2[(s0 +  8) * 64] = A20 + gf + SPLAT(b_lr[s0 +  8]);
    ob2[(s0 +  9) * 64] = A21 + gf + SPLAT(b_lr[s0 +  9]);
    ob2[(s0 + 10) * 64] = A22 + gf + SPLAT(b_lr[s0 + 10]);
    ob2[(s0 + 11) * 64] = A23 + gf + SPLAT(b_lr[s0 + 11]);
}

extern "C" void kernel_launch(void* const* d_in, const int* in_sizes, int n_in,
                              void* d_out, int out_size, void* d_ws, size_t ws_size,
                              hipStream_t stream) {
    const float* x    = (const float*)d_in[0];
    const float* W_le = (const float*)d_in[1];
    const float* b_le = (const float*)d_in[2];
    const float* W_lr = (const float*)d_in[3];
    const float* b_lr = (const float*)d_in[4];
    const float* W_ge = (const float*)d_in[5];
    const float* b_ge = (const float*)d_in[6];
    const float* W_gn = (const float*)d_in[7];
    const float* b_gn = (const float*)d_in[8];
    float* out = (float*)d_out;
    float* gf  = (float*)d_ws;   // 4096*128*4 B = 2 MB scratch

    cle_global<<<4096, 256, 0, stream>>>(x, W_ge, b_ge, W_gn, b_gn, gf);
    cle_local <<<dim3(5, 4096), 64, 0, stream>>>(x, W_le, b_le, W_lr, b_lr, gf, out);
}

// Round 17
// 43.880 us; speedup vs baseline: 1.1599x; 1.1599x over previous
//
#include <hip/hip_runtime.h>

// CharacteristicLineEncoder: B=4096, DIM=3, L=300, S=60, P=5, E=128
// out[b,s,e] = sum_p W_lr[s,p]*relu(W_le[e,:]·x[b,:,5s+p] + b_le[e]) + b_lr[s]
//            + relu( sum_l W_gn[l]*relu(W_ge[e,:]·x[b,:,l] + b_ge[e]) + b_gn )
//
// R15 structure (fused single sweep, 5 balanced waves/block, packed v2f,
// x via wave-uniform s_load, LDS only for the 2.5KB gf exchange) with
// NONTEMPORAL output stores. Rationale (R16 post-mortem): ten structural
// variants all land 45.6-52us while rocclr's fill kernel streams stores at
// 7 TB/s with 10% occupancy -> the gap suspect is L2 write-allocate dirty-
// eviction serialization; nt stores bypass L2 allocation (out is never
// re-read). All other proven mechanics unchanged (rule #20 named accs,
// readfirstlane'd wq, no min-waves arg).

typedef float v2f __attribute__((ext_vector_type(2)));

#define PKFMA(a, b, c) __builtin_elementwise_fma((a), (b), (c))
#define PKRELU(a)      __builtin_elementwise_max((a), (v2f)0.0f)
#define SPLAT(s)       ((v2f)(s))

__global__ __launch_bounds__(320) void cle_kernel(
    const float* __restrict__ x,     // [B,3,300]
    const float* __restrict__ W_le,  // [E,3]
    const float* __restrict__ b_le,  // [E]
    const float* __restrict__ W_lr,  // [300]
    const float* __restrict__ b_lr,  // [60]
    const float* __restrict__ W_ge,  // [E,3]
    const float* __restrict__ b_ge,  // [E]
    const float* __restrict__ W_gn,  // [300]
    const float* __restrict__ b_gn,  // [1]
    float* __restrict__ out)         // [B,60,128]
{
    const int tid  = threadIdx.x;
    const int lane = tid & 63;
    const int wq   = __builtin_amdgcn_readfirstlane(tid >> 6);  // wave 0..4, SGPR
    const int b    = blockIdx.x;
    const int e0   = lane << 1;      // this lane's e-pair

    __shared__ v2f sgp[5][64];       // per-wave global-branch partials (2.5 KB)

    const float* __restrict__ xb = x + (size_t)b * 900;   // uniform base

    // per-lane packed (e0,e1) weights
    const v2f wg0 = {W_ge[e0 * 3 + 0], W_ge[e0 * 3 + 3]};
    const v2f wg1 = {W_ge[e0 * 3 + 1], W_ge[e0 * 3 + 4]};
    const v2f wg2 = {W_ge[e0 * 3 + 2], W_ge[e0 * 3 + 5]};
    const v2f bg  = {b_ge[e0], b_ge[e0 + 1]};
    const v2f wl0 = {W_le[e0 * 3 + 0], W_le[e0 * 3 + 3]};
    const v2f wl1 = {W_le[e0 * 3 + 1], W_le[e0 * 3 + 4]};
    const v2f wl2 = {W_le[e0 * 3 + 2], W_le[e0 * 3 + 5]};
    const v2f bl  = {b_le[e0], b_le[e0 + 1]};
    const float bgn = b_gn[0];

    // global-branch chains (2, packed)
    v2f ga0 = SPLAT(0.f), ga1 = SPLAT(0.f);
    // 12 local accumulators, NAMED, literal indices only
    v2f A00 = SPLAT(0.f), A01 = SPLAT(0.f), A02 = SPLAT(0.f), A03 = SPLAT(0.f);
    v2f A10 = SPLAT(0.f), A11 = SPLAT(0.f), A12 = SPLAT(0.f), A13 = SPLAT(0.f);
    v2f A20 = SPLAT(0.f), A21 = SPLAT(0.f), A22 = SPLAT(0.f), A23 = SPLAT(0.f);

#define GEj(j) PKRELU(PKFMA(wg2, SPLAT(c2##j), PKFMA(wg1, SPLAT(c1##j), PKFMA(wg0, SPLAT(c0##j), bg))))
#define LEj(j) PKRELU(PKFMA(wl2, SPLAT(c2##j), PKFMA(wl1, SPLAT(c1##j), PKFMA(wl0, SPLAT(c0##j), bl))))

    // one quad = 4 l: 12 uniform scalar x-loads (s_load), feed BOTH branches
#define DOQ(qi, A0, A1, A2, A3)                                                \
    {                                                                          \
        const int lq = lbase + (qi) * 4;     /* uniform */                     \
        const float c00 = xb[lq + 0],   c01 = xb[lq + 1];                      \
        const float c02 = xb[lq + 2],   c03 = xb[lq + 3];                      \
        const float c10 = xb[300 + lq + 0], c11 = xb[300 + lq + 1];            \
        const float c12 = xb[300 + lq + 2], c13 = xb[300 + lq + 3];            \
        const float c20 = xb[600 + lq + 0], c21 = xb[600 + lq + 1];            \
        const float c22 = xb[600 + lq + 2], c23 = xb[600 + lq + 3];            \
        ga0 = PKFMA(SPLAT(W_gn[lq + 0]), GEj(0), ga0);                         \
        ga1 = PKFMA(SPLAT(W_gn[lq + 1]), GEj(1), ga1);                         \
        ga0 = PKFMA(SPLAT(W_gn[lq + 2]), GEj(2), ga0);                         \
        ga1 = PKFMA(SPLAT(W_gn[lq + 3]), GEj(3), ga1);                         \
        A0 = PKFMA(SPLAT(W_lr[lq + 0]), LEj(0), A0);                           \
        A1 = PKFMA(SPLAT(W_lr[lq + 1]), LEj(1), A1);                           \
        A2 = PKFMA(SPLAT(W_lr[lq + 2]), LEj(2), A2);                           \
        A3 = PKFMA(SPLAT(W_lr[lq + 3]), LEj(3), A3);                           \
    }

    // wave wq owns l = 60wq .. 60wq+59 = regions 12wq..12wq+11, 3 groups
    // element t = 4*qi + j (l = 60wq + 20g + t), region = 4g + t/5
    {
        const int lbase = wq * 60;           // group 0: regions 12wq+0..3
        DOQ(0, A00, A00, A00, A00)           // t 0..3
        DOQ(1, A00, A01, A01, A01)           // t 4..7
        DOQ(2, A01, A01, A02, A02)           // t 8..11
        DOQ(3, A02, A02, A02, A03)           // t 12..15
        DOQ(4, A03, A03, A03, A03)           // t 16..19
    }
    {
        const int lbase = wq * 60 + 20;      // group 1: regions 12wq+4..7
        DOQ(0, A10, A10, A10, A10)
        DOQ(1, A10, A11, A11, A11)
        DOQ(2, A11, A11, A12, A12)
        DOQ(3, A12, A12, A12, A13)
        DOQ(4, A13, A13, A13, A13)
    }
    {
        const int lbase = wq * 60 + 40;      // group 2: regions 12wq+8..11
        DOQ(0, A20, A20, A20, A20)
        DOQ(1, A20, A21, A21, A21)
        DOQ(2, A21, A21, A22, A22)
        DOQ(3, A22, A22, A22, A23)
        DOQ(4, A23, A23, A23, A23)
    }

    // combine global-branch partials across the 5 waves
    sgp[wq][lane] = ga0 + ga1;
    __syncthreads();

    v2f gf;
    {
        const v2f p0 = sgp[0][lane], p1 = sgp[1][lane], p2 = sgp[2][lane];
        const v2f p3 = sgp[3][lane], p4 = sgp[4][lane];
        gf = PKRELU((((p0 + p1) + (p2 + p3)) + p4) + SPLAT(bgn));
    }

    // ---- stores: NONTEMPORAL (out never re-read; bypass L2 allocation) ----
    v2f* ob2 = (v2f*)(out + (size_t)b * (60 * 128)) + lane;   // + s*64
    const int s0 = wq * 12;                  // uniform -> b_lr scalar
    __builtin_nontemporal_store(A00 + gf + SPLAT(b_lr[s0 +  0]), &ob2[(s0 +  0) * 64]);
    __builtin_nontemporal_store(A01 + gf + SPLAT(b_lr[s0 +  1]), &ob2[(s0 +  1) * 64]);
    __builtin_nontemporal_store(A02 + gf + SPLAT(b_lr[s0 +  2]), &ob2[(s0 +  2) * 64]);
    __builtin_nontemporal_store(A03 + gf + SPLAT(b_lr[s0 +  3]), &ob2[(s0 +  3) * 64]);
    __builtin_nontemporal_store(A10 + gf + SPLAT(b_lr[s0 +  4]), &ob2[(s0 +  4) * 64]);
    __builtin_nontemporal_store(A11 + gf + SPLAT(b_lr[s0 +  5]), &ob2[(s0 +  5) * 64]);
    __builtin_nontemporal_store(A12 + gf + SPLAT(b_lr[s0 +  6]), &ob2[(s0 +  6) * 64]);
    __builtin_nontemporal_store(A13 + gf + SPLAT(b_lr[s0 +  7]), &ob2[(s0 +  7) * 64]);
    __builtin_nontemporal_store(A20 + gf + SPLAT(b_lr[s0 +  8]), &ob2[(s0 +  8) * 64]);
    __builtin_nontemporal_store(A21 + gf + SPLAT(b_lr[s0 +  9]), &ob2[(s0 +  9) * 64]);
    __builtin_nontemporal_store(A22 + gf + SPLAT(b_lr[s0 + 10]), &ob2[(s0 + 10) * 64]);
    __builtin_nontemporal_store(A23 + gf + SPLAT(b_lr[s0 + 11]), &ob2[(s0 + 11) * 64]);
}

extern "C" void kernel_launch(void* const* d_in, const int* in_sizes, int n_in,
                              void* d_out, int out_size, void* d_ws, size_t ws_size,
                              hipStream_t stream) {
    const float* x    = (const float*)d_in[0];
    const float* W_le = (const float*)d_in[1];
    const float* b_le = (const float*)d_in[2];
    const float* W_lr = (const float*)d_in[3];
    const float* b_lr = (const float*)d_in[4];
    const float* W_ge = (const float*)d_in[5];
    const float* b_ge = (const float*)d_in[6];
    const float* W_gn = (const float*)d_in[7];
    const float* b_gn = (const float*)d_in[8];
    float* out = (float*)d_out;

    cle_kernel<<<4096, 320, 0, stream>>>(x, W_le, b_le, W_lr, b_lr,
                                         W_ge, b_ge, W_gn, b_gn, out);
}